// Round 15
// baseline (2343.548 us; speedup 1.0000x reference)
//
#include <hip/hip_runtime.h>
#include <hip/hip_bf16.h>
#include <math.h>

namespace {

constexpr int D  = 128;
constexpr int H  = 8;
constexpr int TN = 64;

__device__ __forceinline__ void gl_lds16(const float4* g, float* l) {
    __builtin_amdgcn_global_load_lds(
        (const __attribute__((address_space(1))) unsigned int*)(g),
        (__attribute__((address_space(3))) unsigned int*)(l), 16, 0, 0);
}
__device__ __forceinline__ unsigned pack_bf2(float a, float b) {
    __hip_bfloat162 h = __float22bfloat162_rn(make_float2(a, b));
    return *reinterpret_cast<unsigned*>(&h);
}
__device__ __forceinline__ float lo_f(unsigned u) { return __uint_as_float(u << 16); }
__device__ __forceinline__ float hi_f(unsigned u) { return __uint_as_float(u & 0xffff0000u); }

// d_ws layout: N_bf16 [128][1024] (256 KB) + M_bf16 [1024][128] (256 KB) + QS f32 [B][1024]

// ---------------- K0: precompute N and M in BF16 ----------------
__global__ __launch_bounds__(256)
void k0_nm(const float* __restrict__ WQ, const float* __restrict__ WK,
           const float* __restrict__ WV, const float* __restrict__ WO,
           unsigned short* __restrict__ Nb, unsigned short* __restrict__ Mb)
{
    const int t = blockIdx.x * 256 + threadIdx.x;   // 0..131071
    {
        const int k = t >> 10, col = t & 1023;
        const int h = col >> 7, d = col & 127;
        const float* wq = WQ + (size_t)k * D + h * 16;
        const float* wk = WK + (size_t)d * D + h * 16;
        float a = 0.f;
        #pragma unroll
        for (int j = 0; j < 16; ++j) a = fmaf(wq[j], wk[j], a);
        Nb[t] = (unsigned short)(pack_bf2(0.25f * a, 0.f) & 0xffffu);
    }
    {
        const int row = t >> 7, e = t & 127;
        const int h = row >> 7, d = row & 127;
        const float* wv = WV + (size_t)d * D + h * 16;
        const float* wo = WO + (size_t)(h * 16) * D + e;
        float a = 0.f;
        #pragma unroll
        for (int j = 0; j < 16; ++j) a = fmaf(wv[j], wo[(size_t)j * D], a);
        Mb[t] = (unsigned short)(pack_bf2(a, 0.f) & 0xffffu);
    }
}

// ---------------- K1: qk = center @ N_bf16  (8 rows/block; halved L2 stream) ----------------
__global__ __launch_bounds__(256)
void k1_qk(const float* __restrict__ center, const unsigned short* __restrict__ Nmat,
           float* __restrict__ qk)
{
    __shared__ float c_lds[8 * 128];
    const int tid = threadIdx.x;
    const size_t rb = (size_t)blockIdx.x * 8;

    ((float4*)c_lds)[tid] = ((const float4*)(center + rb * D))[tid];
    __syncthreads();

    const uint2* Np = (const uint2*)Nmat + tid;     // N row = 256 uint2 (4 bf16 each)
    float4 acc[8];
    #pragma unroll
    for (int r = 0; r < 8; ++r) acc[r] = make_float4(0.f, 0.f, 0.f, 0.f);

    uint2 bufA[4], bufB[4];
    #pragma unroll
    for (int i = 0; i < 4; ++i) bufA[i] = Np[(size_t)i * 256];

    #pragma unroll
    for (int g = 0; g < 32; ++g) {
        uint2* cur = (g & 1) ? bufB : bufA;
        uint2* nxt = (g & 1) ? bufA : bufB;
        if (g < 31) {
            #pragma unroll
            for (int i = 0; i < 4; ++i) nxt[i] = Np[(size_t)(g * 4 + 4 + i) * 256];
        }
        #pragma unroll
        for (int i = 0; i < 4; ++i) {
            const int k = g * 4 + i;
            const uint2 u = cur[i];
            const float4 nv = make_float4(lo_f(u.x), hi_f(u.x), lo_f(u.y), hi_f(u.y));
            #pragma unroll
            for (int r = 0; r < 8; ++r) {
                const float cc = c_lds[r * 128 + k];
                acc[r].x = fmaf(cc, nv.x, acc[r].x);
                acc[r].y = fmaf(cc, nv.y, acc[r].y);
                acc[r].z = fmaf(cc, nv.z, acc[r].z);
                acc[r].w = fmaf(cc, nv.w, acc[r].w);
            }
        }
    }
    #pragma unroll
    for (int r = 0; r < 8; ++r)
        ((float4*)(qk + (rb + r) * 1024))[tid] = acc[r];
}

// ---------------- K2 v7 (r11-proven, UNCHANGED): head-split waves, wave-local softmax ------
__global__ __launch_bounds__(256)
void k2_stream(const float* __restrict__ center, const float* __restrict__ neighbors,
               float* __restrict__ qs /* in: qk, out: s (in-place per batch) */)
{
    __shared__ float nb_lds[TN * 32 * 4];  // 32 KB; f4 slot (t<<5)|(fc^(t&7)); reused for partials
    __shared__ float qk_lds[H * 128];      // 4 KB; ROTATED: f4 slot h*32 + ((fc&7)<<2 | fc>>3)
    __shared__ float c_lds[D];             // 0.5 KB; rotated
    __shared__ float P_lds[TN * 12];       // 3 KB
    __shared__ float red_pc[8];

    const int tid = threadIdx.x;           // 0..255
    const int w   = tid >> 6;              // wave 0..3 (owns heads 2w, 2w+1)
    const int l   = tid & 63;
    const int b   = blockIdx.x;

    float* qsb = qs + (size_t)b * 1024;
    const float4* gnb = (const float4*)(neighbors + (size_t)b * TN * D);

    // ---- stage via global_load_lds: linear LDS dest + pre-swizzled global source ----
    #pragma unroll
    for (int i = 0; i < 8; ++i) {          // nb: 32 chunks of 1KB
        const int k = w * 8 + i;
        const int s = k * 64 + l;
        const int gi = (s & ~31) | ((s & 31) ^ ((s >> 5) & 7));
        gl_lds16(gnb + gi, &nb_lds[k * 256]);
    }
    if (w == 0) {                          // qk: rotated dest via inverse-rotated source
        const float4* qp = (const float4*)qsb;
        #pragma unroll
        for (int m = 0; m < 4; ++m) {
            const int s = m * 64 + l;
            const int rfc = s & 31;
            const int fc = ((rfc & 3) << 3) | (rfc >> 2);   // unrot
            gl_lds16(qp + ((s & ~31) | fc), &qk_lds[m * 256]);
        }
    } else if (w == 1 && l < 32) {         // center: rotated store
        const int fc = ((l & 3) << 3) | (l >> 2);           // unrot(l)
        ((float4*)c_lds)[l] = ((const float4*)(center + (size_t)b * D))[fc];
    }
    __syncthreads();                       // drains vmcnt: everything landed

    const float4* nb4 = (const float4*)nb_lds;
    const float4* qk4 = (const float4*)qk_lds;
    const float4* c4r = (const float4*)c_lds;

    // ---- phase A: wave w scores ALL 64 tokens for heads 2w,2w+1 + wave-local softmax ----
    const int tg = l & 15;                 // token group: tokens tg+16k
    const int q  = l >> 4;                 // d-quarter (8 fc each)
    const int h0 = 2 * w;

    float sc0[4] = {0.f, 0.f, 0.f, 0.f};
    float sc1[4] = {0.f, 0.f, 0.f, 0.f};
    float s0a = 0.f, s0b = 0.f;
    #pragma unroll
    for (int jj = 0; jj < 8; ++jj) {
        const int rfc = (jj << 2) | q;     // rotated slot of fc = q*8+jj (conflict-free across q)
        const int fc  = (q << 3) | jj;
        const float4 kv0 = qk4[h0 * 32 + rfc];
        const float4 kv1 = qk4[(h0 + 1) * 32 + rfc];
        const float4 cc  = c4r[rfc];
        s0a = fmaf(cc.x, kv0.x, fmaf(cc.y, kv0.y, fmaf(cc.z, kv0.z, fmaf(cc.w, kv0.w, s0a))));
        s0b = fmaf(cc.x, kv1.x, fmaf(cc.y, kv1.y, fmaf(cc.z, kv1.z, fmaf(cc.w, kv1.w, s0b))));
        #pragma unroll
        for (int k = 0; k < 4; ++k) {
            const int t = tg + (k << 4);   // strided tokens: t&7 spans 8 values across lanes
            const float4 tv = nb4[(t << 5) | (fc ^ (t & 7))];
            sc0[k] = fmaf(tv.x, kv0.x, fmaf(tv.y, kv0.y, fmaf(tv.z, kv0.z, fmaf(tv.w, kv0.w, sc0[k]))));
            sc1[k] = fmaf(tv.x, kv1.x, fmaf(tv.y, kv1.y, fmaf(tv.z, kv1.z, fmaf(tv.w, kv1.w, sc1[k]))));
        }
    }
    // combine d-quarters (bits 4,5)
    #pragma unroll
    for (int k = 0; k < 4; ++k) {
        sc0[k] += __shfl_xor(sc0[k], 16);  sc0[k] += __shfl_xor(sc0[k], 32);
        sc1[k] += __shfl_xor(sc1[k], 16);  sc1[k] += __shfl_xor(sc1[k], 32);
    }
    s0a += __shfl_xor(s0a, 16);  s0a += __shfl_xor(s0a, 32);
    s0b += __shfl_xor(s0b, 16);  s0b += __shfl_xor(s0b, 32);

    // wave-local softmax over 65 tokens for this wave's 2 heads
    float m0 = fmaxf(fmaxf(sc0[0], sc0[1]), fmaxf(sc0[2], sc0[3]));
    float m1 = fmaxf(fmaxf(sc1[0], sc1[1]), fmaxf(sc1[2], sc1[3]));
    #pragma unroll
    for (int off = 8; off >= 1; off >>= 1) {
        m0 = fmaxf(m0, __shfl_xor(m0, off));
        m1 = fmaxf(m1, __shfl_xor(m1, off));
    }
    m0 = fmaxf(m0, s0a);
    m1 = fmaxf(m1, s0b);
    float e0v[4], e1v[4];
    float sum0 = 0.f, sum1 = 0.f;
    #pragma unroll
    for (int k = 0; k < 4; ++k) {
        e0v[k] = __expf(sc0[k] - m0);  sum0 += e0v[k];
        e1v[k] = __expf(sc1[k] - m1);  sum1 += e1v[k];
    }
    #pragma unroll
    for (int off = 8; off >= 1; off >>= 1) {
        sum0 += __shfl_xor(sum0, off);
        sum1 += __shfl_xor(sum1, off);
    }
    const float ec0 = __expf(s0a - m0);
    const float ec1 = __expf(s0b - m1);
    const float inv0 = 1.0f / (sum0 + ec0);
    const float inv1 = 1.0f / (sum1 + ec1);
    if (q == 0) {
        #pragma unroll
        for (int k = 0; k < 4; ++k) {
            const int t = tg + (k << 4);
            *reinterpret_cast<float2*>(&P_lds[t * 12 + h0]) =
                make_float2(e0v[k] * inv0, e1v[k] * inv1);
        }
        if (tg == 0) {
            red_pc[h0]     = ec0 * inv0;
            red_pc[h0 + 1] = ec1 * inv1;
        }
    }
    __syncthreads();

    // ---- phase D: wave w sums its 16 tokens; lane = (h-half, f4 col) ----
    const int hl  = l >> 5;
    const int fc2 = l & 31;
    float4 pacc[4];
    #pragma unroll
    for (int j = 0; j < 4; ++j) pacc[j] = make_float4(0.f, 0.f, 0.f, 0.f);
    #pragma unroll
    for (int tt = 0; tt < 16; ++tt) {
        const int t = w * 16 + tt;
        const float4 tv = nb4[(t << 5) | (fc2 ^ (t & 7))];
        const float4 pv = ((const float4*)P_lds)[t * 3 + hl];
        pacc[0].x = fmaf(pv.x, tv.x, pacc[0].x); pacc[0].y = fmaf(pv.x, tv.y, pacc[0].y);
        pacc[0].z = fmaf(pv.x, tv.z, pacc[0].z); pacc[0].w = fmaf(pv.x, tv.w, pacc[0].w);
        pacc[1].x = fmaf(pv.y, tv.x, pacc[1].x); pacc[1].y = fmaf(pv.y, tv.y, pacc[1].y);
        pacc[1].z = fmaf(pv.y, tv.z, pacc[1].z); pacc[1].w = fmaf(pv.y, tv.w, pacc[1].w);
        pacc[2].x = fmaf(pv.z, tv.x, pacc[2].x); pacc[2].y = fmaf(pv.z, tv.y, pacc[2].y);
        pacc[2].z = fmaf(pv.z, tv.z, pacc[2].z); pacc[2].w = fmaf(pv.z, tv.w, pacc[2].w);
        pacc[3].x = fmaf(pv.w, tv.x, pacc[3].x); pacc[3].y = fmaf(pv.w, tv.y, pacc[3].y);
        pacc[3].z = fmaf(pv.w, tv.z, pacc[3].z); pacc[3].w = fmaf(pv.w, tv.w, pacc[3].w);
    }
    // partials into this wave's OWN (dead) nb rows
    #pragma unroll
    for (int j = 0; j < 4; ++j)
        ((float4*)nb_lds)[w * 512 + (hl * 4 + j) * 33 + fc2] = pacc[j];
    __syncthreads();

    // ---- phase E: combine partials + center seed; coalesced write s ----
    {
        const int h = tid >> 5;
        const int f = tid & 31;
        float4 sum = make_float4(0.f, 0.f, 0.f, 0.f);
        #pragma unroll
        for (int ww = 0; ww < 4; ++ww) {
            const float4 p = nb4[ww * 512 + h * 33 + f];
            sum.x += p.x; sum.y += p.y; sum.z += p.z; sum.w += p.w;
        }
        const float pc = red_pc[h];
        const int rf = ((f & 7) << 2) | (f >> 3);   // rot(f)
        const float4 cc = c4r[rf];
        sum.x = fmaf(pc, cc.x, sum.x);
        sum.y = fmaf(pc, cc.y, sum.y);
        sum.z = fmaf(pc, cc.z, sum.z);
        sum.w = fmaf(pc, cc.w, sum.w);
        ((float4*)qsb)[tid] = sum;
    }
}

// ---------------- K3: out = s @ M_bf16  (8 rows/block; halved L2 stream) ----------------
__global__ __launch_bounds__(256)
void k3_out(const float* __restrict__ qs, const unsigned short* __restrict__ Mmat,
            float* __restrict__ out)
{
    __shared__ float s_lds[8 * 1024];
    const int tid = threadIdx.x;
    const size_t rb = (size_t)blockIdx.x * 8;

    {
        const float4* sp = (const float4*)(qs + rb * 1024);
        #pragma unroll
        for (int i = 0; i < 8; ++i)
            ((float4*)s_lds)[i * 256 + tid] = sp[i * 256 + tid];
    }
    __syncthreads();

    const int cg = tid & 31;
    const int kg = tid >> 5;
    const int c4 = cg << 2;
    const int kbase = kg << 7;
    const int rot = kg << 2;

    float4 acc[8];
    #pragma unroll
    for (int r = 0; r < 8; ++r) acc[r] = make_float4(0.f, 0.f, 0.f, 0.f);

    const uint2* Mp2 = (const uint2*)Mmat;    // M row = 32 uint2 (4 bf16 each)

    uint2 bA[4], bB[4];
    #pragma unroll
    for (int i = 0; i < 4; ++i) {
        const int k = kbase + ((0 * 4 + i + rot) & 127);
        bA[i] = Mp2[(size_t)k * 32 + cg];
    }
    #pragma unroll
    for (int g = 0; g < 32; ++g) {
        uint2* cur = (g & 1) ? bB : bA;
        uint2* nxt = (g & 1) ? bA : bB;
        if (g < 31) {
            #pragma unroll
            for (int i = 0; i < 4; ++i) {
                const int k = kbase + ((g * 4 + 4 + i + rot) & 127);
                nxt[i] = Mp2[(size_t)k * 32 + cg];
            }
        }
        #pragma unroll
        for (int i = 0; i < 4; ++i) {
            const int k = kbase + ((g * 4 + i + rot) & 127);
            const uint2 u = cur[i];
            const float4 mv = make_float4(lo_f(u.x), hi_f(u.x), lo_f(u.y), hi_f(u.y));
            #pragma unroll
            for (int r = 0; r < 8; ++r) {
                const float sv = s_lds[r * 1024 + k];
                acc[r].x = fmaf(sv, mv.x, acc[r].x);
                acc[r].y = fmaf(sv, mv.y, acc[r].y);
                acc[r].z = fmaf(sv, mv.z, acc[r].z);
                acc[r].w = fmaf(sv, mv.w, acc[r].w);
            }
        }
    }
    __syncthreads();
    float* part = s_lds;
    #pragma unroll
    for (int r = 0; r < 8; ++r)
        *reinterpret_cast<float4*>(&part[(kg * 8 + r) * 128 + c4]) = acc[r];
    __syncthreads();

    {
        const int r = tid >> 5;
        float4 sum = make_float4(0.f, 0.f, 0.f, 0.f);
        #pragma unroll
        for (int g = 0; g < 8; ++g) {
            const float4 p = *reinterpret_cast<const float4*>(&part[(g * 8 + r) * 128 + c4]);
            sum.x += p.x; sum.y += p.y; sum.z += p.z; sum.w += p.w;
        }
        *reinterpret_cast<float4*>(out + (rb + r) * D + c4) = sum;
    }
}

} // namespace

extern "C" void kernel_launch(void* const* d_in, const int* in_sizes, int n_in,
                              void* d_out, int out_size, void* d_ws, size_t ws_size,
                              hipStream_t stream) {
    const float* center    = (const float*)d_in[0];
    const float* neighbors = (const float*)d_in[1];
    const float* WQ        = (const float*)d_in[2];
    const float* WK        = (const float*)d_in[3];
    const float* WV        = (const float*)d_in[4];
    const float* WO        = (const float*)d_in[5];
    float* outp            = (float*)d_out;

    const int B = in_sizes[0] / D;   // 8192

    unsigned short* Nb = (unsigned short*)d_ws;          // 128*1024 bf16 (256 KB)
    unsigned short* Mb = Nb + 128 * 1024;                // 1024*128 bf16 (256 KB)
    float* QS          = (float*)(Mb + 1024 * 128);      // B*1024 f32 (qk, then s in-place)

    hipLaunchKernelGGL(k0_nm,    dim3(512),   dim3(256), 0, stream, WQ, WK, WV, WO, Nb, Mb);
    hipLaunchKernelGGL(k1_qk,    dim3(B / 8), dim3(256), 0, stream, center, Nb, QS);
    hipLaunchKernelGGL(k2_stream,dim3(B),     dim3(256), 0, stream, center, neighbors, QS);
    hipLaunchKernelGGL(k3_out,   dim3(B / 8), dim3(256), 0, stream, QS, Mb, outp);
}

// Round 16
// 139.632 us; speedup vs baseline: 16.7837x; 16.7837x over previous
//
#include <hip/hip_runtime.h>
#include <hip/hip_bf16.h>
#include <math.h>

namespace {

constexpr int D  = 128;
constexpr int H  = 8;
constexpr int TN = 64;

__device__ __forceinline__ void gl_lds16(const float4* g, float* l) {
    __builtin_amdgcn_global_load_lds(
        (const __attribute__((address_space(1))) unsigned int*)(g),
        (__attribute__((address_space(3))) unsigned int*)(l), 16, 0, 0);
}
__device__ __forceinline__ unsigned pack_bf2(float a, float b) {
    __hip_bfloat162 h = __float22bfloat162_rn(make_float2(a, b));
    return *reinterpret_cast<unsigned*>(&h);
}
__device__ __forceinline__ float lo_f(unsigned u) { return __uint_as_float(u << 16); }
__device__ __forceinline__ float hi_f(unsigned u) { return __uint_as_float(u & 0xffff0000u); }

// d_ws layout: N_bf16 [128][1024] (256 KB) + M_bf16 [1024][128] (256 KB) + QS f32 [B][1024]

// ---------------- K0: precompute N and M in BF16 ----------------
__global__ __launch_bounds__(256)
void k0_nm(const float* __restrict__ WQ, const float* __restrict__ WK,
           const float* __restrict__ WV, const float* __restrict__ WO,
           unsigned short* __restrict__ Nb, unsigned short* __restrict__ Mb)
{
    const int t = blockIdx.x * 256 + threadIdx.x;   // 0..131071
    {
        const int k = t >> 10, col = t & 1023;
        const int h = col >> 7, d = col & 127;
        const float* wq = WQ + (size_t)k * D + h * 16;
        const float* wk = WK + (size_t)d * D + h * 16;
        float a = 0.f;
        #pragma unroll
        for (int j = 0; j < 16; ++j) a = fmaf(wq[j], wk[j], a);
        Nb[t] = (unsigned short)(pack_bf2(0.25f * a, 0.f) & 0xffffu);
    }
    {
        const int row = t >> 7, e = t & 127;
        const int h = row >> 7, d = row & 127;
        const float* wv = WV + (size_t)d * D + h * 16;
        const float* wo = WO + (size_t)(h * 16) * D + e;
        float a = 0.f;
        #pragma unroll
        for (int j = 0; j < 16; ++j) a = fmaf(wv[j], wo[(size_t)j * D], a);
        Mb[t] = (unsigned short)(pack_bf2(a, 0.f) & 0xffffu);
    }
}

// ---------------- K1: qk = center @ N_bf16 (simple loop, unroll 4 — no hoist blowup) -------
__global__ __launch_bounds__(256)
void k1_qk(const float* __restrict__ center, const unsigned short* __restrict__ Nmat,
           float* __restrict__ qk)
{
    __shared__ float c_lds[8 * 128];
    const int tid = threadIdx.x;
    const size_t rb = (size_t)blockIdx.x * 8;

    ((float4*)c_lds)[tid] = ((const float4*)(center + rb * D))[tid];
    __syncthreads();

    const uint2* Np = (const uint2*)Nmat + tid;     // N row = 256 uint2 (4 bf16)
    float4 acc[8];
    #pragma unroll
    for (int r = 0; r < 8; ++r) acc[r] = make_float4(0.f, 0.f, 0.f, 0.f);

    #pragma unroll 4
    for (int k = 0; k < 128; ++k) {
        const uint2 u = Np[(size_t)k * 256];
        const float4 nv = make_float4(lo_f(u.x), hi_f(u.x), lo_f(u.y), hi_f(u.y));
        #pragma unroll
        for (int r = 0; r < 8; ++r) {
            const float cc = c_lds[r * 128 + k];
            acc[r].x = fmaf(cc, nv.x, acc[r].x);
            acc[r].y = fmaf(cc, nv.y, acc[r].y);
            acc[r].z = fmaf(cc, nv.z, acc[r].z);
            acc[r].w = fmaf(cc, nv.w, acc[r].w);
        }
    }
    #pragma unroll
    for (int r = 0; r < 8; ++r)
        ((float4*)(qk + (rb + r) * 1024))[tid] = acc[r];
}

// ---------------- K2 v7 (r11-proven, UNCHANGED): head-split waves, wave-local softmax ------
__global__ __launch_bounds__(256)
void k2_stream(const float* __restrict__ center, const float* __restrict__ neighbors,
               float* __restrict__ qs /* in: qk, out: s (in-place per batch) */)
{
    __shared__ float nb_lds[TN * 32 * 4];  // 32 KB; f4 slot (t<<5)|(fc^(t&7)); reused for partials
    __shared__ float qk_lds[H * 128];      // 4 KB; ROTATED: f4 slot h*32 + ((fc&7)<<2 | fc>>3)
    __shared__ float c_lds[D];             // 0.5 KB; rotated
    __shared__ float P_lds[TN * 12];       // 3 KB
    __shared__ float red_pc[8];

    const int tid = threadIdx.x;           // 0..255
    const int w   = tid >> 6;              // wave 0..3 (owns heads 2w, 2w+1)
    const int l   = tid & 63;
    const int b   = blockIdx.x;

    float* qsb = qs + (size_t)b * 1024;
    const float4* gnb = (const float4*)(neighbors + (size_t)b * TN * D);

    // ---- stage via global_load_lds: linear LDS dest + pre-swizzled global source ----
    #pragma unroll
    for (int i = 0; i < 8; ++i) {          // nb: 32 chunks of 1KB
        const int k = w * 8 + i;
        const int s = k * 64 + l;
        const int gi = (s & ~31) | ((s & 31) ^ ((s >> 5) & 7));
        gl_lds16(gnb + gi, &nb_lds[k * 256]);
    }
    if (w == 0) {                          // qk: rotated dest via inverse-rotated source
        const float4* qp = (const float4*)qsb;
        #pragma unroll
        for (int m = 0; m < 4; ++m) {
            const int s = m * 64 + l;
            const int rfc = s & 31;
            const int fc = ((rfc & 3) << 3) | (rfc >> 2);   // unrot
            gl_lds16(qp + ((s & ~31) | fc), &qk_lds[m * 256]);
        }
    } else if (w == 1 && l < 32) {         // center: rotated store
        const int fc = ((l & 3) << 3) | (l >> 2);           // unrot(l)
        ((float4*)c_lds)[l] = ((const float4*)(center + (size_t)b * D))[fc];
    }
    __syncthreads();                       // drains vmcnt: everything landed

    const float4* nb4 = (const float4*)nb_lds;
    const float4* qk4 = (const float4*)qk_lds;
    const float4* c4r = (const float4*)c_lds;

    // ---- phase A: wave w scores ALL 64 tokens for heads 2w,2w+1 + wave-local softmax ----
    const int tg = l & 15;                 // token group: tokens tg+16k
    const int q  = l >> 4;                 // d-quarter (8 fc each)
    const int h0 = 2 * w;

    float sc0[4] = {0.f, 0.f, 0.f, 0.f};
    float sc1[4] = {0.f, 0.f, 0.f, 0.f};
    float s0a = 0.f, s0b = 0.f;
    #pragma unroll
    for (int jj = 0; jj < 8; ++jj) {
        const int rfc = (jj << 2) | q;     // rotated slot of fc = q*8+jj (conflict-free across q)
        const int fc  = (q << 3) | jj;
        const float4 kv0 = qk4[h0 * 32 + rfc];
        const float4 kv1 = qk4[(h0 + 1) * 32 + rfc];
        const float4 cc  = c4r[rfc];
        s0a = fmaf(cc.x, kv0.x, fmaf(cc.y, kv0.y, fmaf(cc.z, kv0.z, fmaf(cc.w, kv0.w, s0a))));
        s0b = fmaf(cc.x, kv1.x, fmaf(cc.y, kv1.y, fmaf(cc.z, kv1.z, fmaf(cc.w, kv1.w, s0b))));
        #pragma unroll
        for (int k = 0; k < 4; ++k) {
            const int t = tg + (k << 4);   // strided tokens: t&7 spans 8 values across lanes
            const float4 tv = nb4[(t << 5) | (fc ^ (t & 7))];
            sc0[k] = fmaf(tv.x, kv0.x, fmaf(tv.y, kv0.y, fmaf(tv.z, kv0.z, fmaf(tv.w, kv0.w, sc0[k]))));
            sc1[k] = fmaf(tv.x, kv1.x, fmaf(tv.y, kv1.y, fmaf(tv.z, kv1.z, fmaf(tv.w, kv1.w, sc1[k]))));
        }
    }
    // combine d-quarters (bits 4,5)
    #pragma unroll
    for (int k = 0; k < 4; ++k) {
        sc0[k] += __shfl_xor(sc0[k], 16);  sc0[k] += __shfl_xor(sc0[k], 32);
        sc1[k] += __shfl_xor(sc1[k], 16);  sc1[k] += __shfl_xor(sc1[k], 32);
    }
    s0a += __shfl_xor(s0a, 16);  s0a += __shfl_xor(s0a, 32);
    s0b += __shfl_xor(s0b, 16);  s0b += __shfl_xor(s0b, 32);

    // wave-local softmax over 65 tokens for this wave's 2 heads
    float m0 = fmaxf(fmaxf(sc0[0], sc0[1]), fmaxf(sc0[2], sc0[3]));
    float m1 = fmaxf(fmaxf(sc1[0], sc1[1]), fmaxf(sc1[2], sc1[3]));
    #pragma unroll
    for (int off = 8; off >= 1; off >>= 1) {
        m0 = fmaxf(m0, __shfl_xor(m0, off));
        m1 = fmaxf(m1, __shfl_xor(m1, off));
    }
    m0 = fmaxf(m0, s0a);
    m1 = fmaxf(m1, s0b);
    float e0v[4], e1v[4];
    float sum0 = 0.f, sum1 = 0.f;
    #pragma unroll
    for (int k = 0; k < 4; ++k) {
        e0v[k] = __expf(sc0[k] - m0);  sum0 += e0v[k];
        e1v[k] = __expf(sc1[k] - m1);  sum1 += e1v[k];
    }
    #pragma unroll
    for (int off = 8; off >= 1; off >>= 1) {
        sum0 += __shfl_xor(sum0, off);
        sum1 += __shfl_xor(sum1, off);
    }
    const float ec0 = __expf(s0a - m0);
    const float ec1 = __expf(s0b - m1);
    const float inv0 = 1.0f / (sum0 + ec0);
    const float inv1 = 1.0f / (sum1 + ec1);
    if (q == 0) {
        #pragma unroll
        for (int k = 0; k < 4; ++k) {
            const int t = tg + (k << 4);
            *reinterpret_cast<float2*>(&P_lds[t * 12 + h0]) =
                make_float2(e0v[k] * inv0, e1v[k] * inv1);
        }
        if (tg == 0) {
            red_pc[h0]     = ec0 * inv0;
            red_pc[h0 + 1] = ec1 * inv1;
        }
    }
    __syncthreads();

    // ---- phase D: wave w sums its 16 tokens; lane = (h-half, f4 col) ----
    const int hl  = l >> 5;
    const int fc2 = l & 31;
    float4 pacc[4];
    #pragma unroll
    for (int j = 0; j < 4; ++j) pacc[j] = make_float4(0.f, 0.f, 0.f, 0.f);
    #pragma unroll
    for (int tt = 0; tt < 16; ++tt) {
        const int t = w * 16 + tt;
        const float4 tv = nb4[(t << 5) | (fc2 ^ (t & 7))];
        const float4 pv = ((const float4*)P_lds)[t * 3 + hl];
        pacc[0].x = fmaf(pv.x, tv.x, pacc[0].x); pacc[0].y = fmaf(pv.x, tv.y, pacc[0].y);
        pacc[0].z = fmaf(pv.x, tv.z, pacc[0].z); pacc[0].w = fmaf(pv.x, tv.w, pacc[0].w);
        pacc[1].x = fmaf(pv.y, tv.x, pacc[1].x); pacc[1].y = fmaf(pv.y, tv.y, pacc[1].y);
        pacc[1].z = fmaf(pv.y, tv.z, pacc[1].z); pacc[1].w = fmaf(pv.y, tv.w, pacc[1].w);
        pacc[2].x = fmaf(pv.z, tv.x, pacc[2].x); pacc[2].y = fmaf(pv.z, tv.y, pacc[2].y);
        pacc[2].z = fmaf(pv.z, tv.z, pacc[2].z); pacc[2].w = fmaf(pv.z, tv.w, pacc[2].w);
        pacc[3].x = fmaf(pv.w, tv.x, pacc[3].x); pacc[3].y = fmaf(pv.w, tv.y, pacc[3].y);
        pacc[3].z = fmaf(pv.w, tv.z, pacc[3].z); pacc[3].w = fmaf(pv.w, tv.w, pacc[3].w);
    }
    // partials into this wave's OWN (dead) nb rows
    #pragma unroll
    for (int j = 0; j < 4; ++j)
        ((float4*)nb_lds)[w * 512 + (hl * 4 + j) * 33 + fc2] = pacc[j];
    __syncthreads();

    // ---- phase E: combine partials + center seed; coalesced write s ----
    {
        const int h = tid >> 5;
        const int f = tid & 31;
        float4 sum = make_float4(0.f, 0.f, 0.f, 0.f);
        #pragma unroll
        for (int ww = 0; ww < 4; ++ww) {
            const float4 p = nb4[ww * 512 + h * 33 + f];
            sum.x += p.x; sum.y += p.y; sum.z += p.z; sum.w += p.w;
        }
        const float pc = red_pc[h];
        const int rf = ((f & 7) << 2) | (f >> 3);   // rot(f)
        const float4 cc = c4r[rf];
        sum.x = fmaf(pc, cc.x, sum.x);
        sum.y = fmaf(pc, cc.y, sum.y);
        sum.z = fmaf(pc, cc.z, sum.z);
        sum.w = fmaf(pc, cc.w, sum.w);
        ((float4*)qsb)[tid] = sum;
    }
}

// ---------------- K3: out = s @ M_bf16 (simple loop, unroll 4 — no hoist blowup) ----------
__global__ __launch_bounds__(256)
void k3_out(const float* __restrict__ qs, const unsigned short* __restrict__ Mmat,
            float* __restrict__ out)
{
    __shared__ float s_lds[8 * 1024];
    const int tid = threadIdx.x;
    const size_t rb = (size_t)blockIdx.x * 8;

    {
        const float4* sp = (const float4*)(qs + rb * 1024);
        #pragma unroll
        for (int i = 0; i < 8; ++i)
            ((float4*)s_lds)[i * 256 + tid] = sp[i * 256 + tid];
    }
    __syncthreads();

    const int cg = tid & 31;          // column group: cols cg*4..cg*4+3
    const int kg = tid >> 5;          // k-split group 0..7 (k-range kg*128..+127)
    const int c4 = cg << 2;
    const int kbase = kg << 7;

    float4 acc[8];
    #pragma unroll
    for (int r = 0; r < 8; ++r) acc[r] = make_float4(0.f, 0.f, 0.f, 0.f);

    const uint2* Mp2 = (const uint2*)Mmat;    // M row = 32 uint2 (4 bf16)

    #pragma unroll 4
    for (int ki = 0; ki < 128; ++ki) {
        const int k = kbase + ki;
        const uint2 u = Mp2[(size_t)k * 32 + cg];
        const float4 mv = make_float4(lo_f(u.x), hi_f(u.x), lo_f(u.y), hi_f(u.y));
        #pragma unroll
        for (int r = 0; r < 8; ++r) {
            const float sv = s_lds[r * 1024 + k];
            acc[r].x = fmaf(sv, mv.x, acc[r].x);
            acc[r].y = fmaf(sv, mv.y, acc[r].y);
            acc[r].z = fmaf(sv, mv.z, acc[r].z);
            acc[r].w = fmaf(sv, mv.w, acc[r].w);
        }
    }
    __syncthreads();                  // all s_lds reads done; reuse as partials
    float* part = s_lds;              // part[kg][r][128]
    #pragma unroll
    for (int r = 0; r < 8; ++r)
        *reinterpret_cast<float4*>(&part[(kg * 8 + r) * 128 + c4]) = acc[r];
    __syncthreads();

    {
        const int r = tid >> 5;
        float4 sum = make_float4(0.f, 0.f, 0.f, 0.f);
        #pragma unroll
        for (int g = 0; g < 8; ++g) {
            const float4 p = *reinterpret_cast<const float4*>(&part[(g * 8 + r) * 128 + c4]);
            sum.x += p.x; sum.y += p.y; sum.z += p.z; sum.w += p.w;
        }
        *reinterpret_cast<float4*>(out + (rb + r) * D + c4) = sum;
    }
}

} // namespace

extern "C" void kernel_launch(void* const* d_in, const int* in_sizes, int n_in,
                              void* d_out, int out_size, void* d_ws, size_t ws_size,
                              hipStream_t stream) {
    const float* center    = (const float*)d_in[0];
    const float* neighbors = (const float*)d_in[1];
    const float* WQ        = (const float*)d_in[2];
    const float* WK        = (const float*)d_in[3];
    const float* WV        = (const float*)d_in[4];
    const float* WO        = (const float*)d_in[5];
    float* outp            = (float*)d_out;

    const int B = in_sizes[0] / D;   // 8192

    unsigned short* Nb = (unsigned short*)d_ws;          // 128*1024 bf16 (256 KB)
    unsigned short* Mb = Nb + 128 * 1024;                // 1024*128 bf16 (256 KB)
    float* QS          = (float*)(Mb + 1024 * 128);      // B*1024 f32 (qk, then s in-place)

    hipLaunchKernelGGL(k0_nm,    dim3(512),   dim3(256), 0, stream, WQ, WK, WV, WO, Nb, Mb);
    hipLaunchKernelGGL(k1_qk,    dim3(B / 8), dim3(256), 0, stream, center, Nb, QS);
    hipLaunchKernelGGL(k2_stream,dim3(B),     dim3(256), 0, stream, center, neighbors, QS);
    hipLaunchKernelGGL(k3_out,   dim3(B / 8), dim3(256), 0, stream, QS, Mb, outp);
}